// Round 10
// baseline (622.485 us; speedup 1.0000x reference)
//
#include <hip/hip_runtime.h>

#define N_NODES 100000
#define N_EDGES 1600000
#define N_GRAPHS 2048
#define DIM 128

// bucket CSR build params
#define NBUK 196      // ceil(100000/512)
#define BUKSH 9       // bucket = dst >> 9 (512 nodes per bucket)
#define NCH 256       // edge chunks (blocks) in passes A/C
#define EPB 6250      // edges per chunk = N_EDGES / NCH
#define NMAT (NBUK * NCH)  // 50176

typedef short short8v __attribute__((ext_vector_type(8)));
typedef float float4v __attribute__((ext_vector_type(4)));

__device__ __forceinline__ unsigned short f2bf(float f) {
  union { float f; unsigned u; } x; x.f = f;
  unsigned r = x.u + 0x7fffu + ((x.u >> 16) & 1u);
  return (unsigned short)(r >> 16);
}
__device__ __forceinline__ float bfhi2f(unsigned bits) {  // bits already in high half
  union { unsigned u; float f; } x; x.u = bits; return x.f;
}
__device__ __forceinline__ void accum8(float* p, uint4 v) {
  p[0] += bfhi2f(v.x << 16); p[1] += bfhi2f(v.x & 0xffff0000u);
  p[2] += bfhi2f(v.y << 16); p[3] += bfhi2f(v.y & 0xffff0000u);
  p[4] += bfhi2f(v.z << 16); p[5] += bfhi2f(v.z & 0xffff0000u);
  p[6] += bfhi2f(v.w << 16); p[7] += bfhi2f(v.w & 0xffff0000u);
}

// ---------------- bucket CSR build (zero global atomics) ----------------
__global__ __launch_bounds__(256) void k_bcount(const int* __restrict__ dst, int* __restrict__ cntmat) {
  __shared__ int cnt[NBUK];
  int b = blockIdx.x, t = threadIdx.x;
  if (t < NBUK) cnt[t] = 0;
  __syncthreads();
  int e0 = b * EPB;
  for (int j = t; j < EPB; j += 256) atomicAdd(&cnt[dst[e0 + j] >> BUKSH], 1);
  __syncthreads();
  if (t < NBUK) cntmat[t * NCH + b] = cnt[t];
}

// generic scan (chunk = 1024/block)
__global__ __launch_bounds__(256) void k_scan1g(const int* __restrict__ in, int n,
                                                int* __restrict__ tmp, int* __restrict__ bsum) {
  __shared__ int sh[256];
  int b = blockIdx.x, t = threadIdx.x;
  int base = b * 1024 + t * 4;
  int v[4], s = 0;
#pragma unroll
  for (int i = 0; i < 4; i++) { v[i] = (base + i < n) ? in[base + i] : 0; s += v[i]; }
  sh[t] = s;
  __syncthreads();
  for (int off = 1; off < 256; off <<= 1) {
    int x = (t >= off) ? sh[t - off] : 0;
    __syncthreads();
    sh[t] += x;
    __syncthreads();
  }
  int run = sh[t] - s;
#pragma unroll
  for (int i = 0; i < 4; i++) { run += v[i]; if (base + i < n) tmp[base + i] = run; }
  if (t == 255) bsum[b] = sh[255];
}

__global__ void k_scan2g(int* __restrict__ bsum, int nb) {
  __shared__ int sh[128];
  int t = threadIdx.x;
  int v = (t < nb) ? bsum[t] : 0;
  sh[t] = v;
  __syncthreads();
  for (int off = 1; off < 128; off <<= 1) {
    int x = (t >= off) ? sh[t - off] : 0;
    __syncthreads();
    sh[t] += x;
    __syncthreads();
  }
  if (t < nb) bsum[t] = sh[t] - v;  // exclusive
}

__global__ __launch_bounds__(256) void k_exc(const int* __restrict__ tmp, const int* __restrict__ bsum,
                                             const int* __restrict__ in, int n, int* __restrict__ outExc) {
  int i = blockIdx.x * 256 + threadIdx.x;
  if (i < n) outExc[i] = tmp[i] + bsum[i >> 10] - in[i];
}

__global__ __launch_bounds__(256) void k_bscatter(const int* __restrict__ src, const int* __restrict__ dst,
                                                  const int* __restrict__ base, int2* __restrict__ epk) {
  __shared__ int cur[NBUK];
  int b = blockIdx.x, t = threadIdx.x;
  if (t < NBUK) cur[t] = base[t * NCH + b];
  __syncthreads();
  int e0 = b * EPB;
  for (int j = t; j < EPB; j += 256) {
    int s = src[e0 + j], d = dst[e0 + j];
    int pos = atomicAdd(&cur[d >> BUKSH], 1);
    epk[pos] = make_int2(s, d);
  }
}

__global__ __launch_bounds__(256) void k_bfinish(const int2* __restrict__ epk, const int* __restrict__ base,
                                                 int* __restrict__ rowptr, int* __restrict__ col) {
  __shared__ int a[512];
  __shared__ int sh[256];
  int k = blockIdx.x, t = threadIdx.x;
  int bstart = base[k * NCH];
  int bend = (k + 1 < NBUK) ? base[(k + 1) * NCH] : N_EDGES;
  a[t] = 0; a[t + 256] = 0;
  __syncthreads();
  for (int i = bstart + t; i < bend; i += 256) atomicAdd(&a[epk[i].y - (k << BUKSH)], 1);
  __syncthreads();
  int c0 = a[2 * t], c1 = a[2 * t + 1];
  int s = c0 + c1;
  sh[t] = s;
  __syncthreads();
  for (int off = 1; off < 256; off <<= 1) {
    int x = (t >= off) ? sh[t - off] : 0;
    __syncthreads();
    sh[t] += x;
    __syncthreads();
  }
  int excl = sh[t] - s;
  int st0 = bstart + excl;
  int st1 = st0 + c0;
  int g0 = (k << BUKSH) + 2 * t, g1 = g0 + 1;
  if (g0 < N_NODES) rowptr[g0] = st0;
  if (g1 < N_NODES) rowptr[g1] = st1;
  if (k == NBUK - 1 && t == 0) rowptr[N_NODES] = N_EDGES;
  __syncthreads();
  a[2 * t] = st0; a[2 * t + 1] = st1;  // convert to cursors
  __syncthreads();
  for (int i = bstart + t; i < bend; i += 256) {
    int2 e = epk[i];
    int pos = atomicAdd(&a[e.y - (k << BUKSH)], 1);
    col[pos] = e.x;
  }
}

// ---------------- graph boundary pointers (batch is sorted) ----------------
__global__ __launch_bounds__(256) void k_gptr(const int* __restrict__ batch, int* __restrict__ gptr) {
  int i = blockIdx.x * 256 + threadIdx.x;
  if (i >= N_NODES) return;
  int b = batch[i];
  int a = (i == 0) ? -1 : batch[i - 1];
  for (int g = a + 1; g <= b; g++) gptr[g] = i;
  if (i == N_NODES - 1) {
    for (int g = b + 1; g <= N_GRAPHS; g++) gptr[g] = N_NODES;
  }
}

// ---------------- dtype converts ----------------
__global__ __launch_bounds__(256) void k_cvtx(const float* __restrict__ x, unsigned short* __restrict__ h) {
  int i = blockIdx.x * 256 + threadIdx.x;  // over N*DIM/4
  if (i < N_NODES * DIM / 4) {
    float4 v = ((const float4*)x)[i];
    unsigned lo = (unsigned)f2bf(v.x) | ((unsigned)f2bf(v.y) << 16);
    unsigned hi = (unsigned)f2bf(v.z) | ((unsigned)f2bf(v.w) << 16);
    ((uint2*)h)[i] = make_uint2(lo, hi);
  }
}

// Weights -> bf16 MFMA B-fragment order.
__global__ __launch_bounds__(256) void k_cvtw(const float* w0, const float* w1, const float* w2, const float* w3,
                                              const float* w4, const float* w5, const float* w6, const float* w7,
                                              unsigned short* __restrict__ wbF) {
  int i = blockIdx.x * 256 + threadIdx.x;
  if (i < 4 * 8 * 8 * 64 * 8) {
    int j = i & 7, l = (i >> 3) & 63, c = (i >> 9) & 7, kc = (i >> 12) & 7, layer = i >> 15;
    int m = layer * 2 + (kc >> 2);
    const float* w;
    switch (m) {
      case 0: w = w0; break; case 1: w = w1; break; case 2: w = w2; break; case 3: w = w3; break;
      case 4: w = w4; break; case 5: w = w5; break; case 6: w = w6; break; default: w = w7; break;
    }
    int kin = (kc & 3) * 32 + ((l >> 4) * 8) + j;
    int n = c * 16 + (l & 15);
    wbF[i] = f2bf(w[kin * 128 + n]);
  }
}

// ---------------- fused layer: h' = relu(segsum(h)[dst] @ Wrel + h @ Wroot + b) ----------------
// 512 thr = 8 waves, 128 rows/block, 16 rows/wave. Each wave is autonomous:
//   gather agg for its 16 rows (k_agg inner loop) -> own 4KB LDS slice (frag layout)
//   -> 4 kc MFMA vs Wrel -> restage its 16 h rows into same slice -> 4 kc MFMA vs Wroot.
// LDS chunk addr: (wave*16 + c)*16 + (r ^ c), c = k>>3 (0..15), r = row within wave tile.
// All LDS phases <=2-way bank aliased (free). __syncthreads only for lane-visibility.
__global__ __launch_bounds__(512, 4) void k_fused(const int* __restrict__ rowptr,
                                                  const int* __restrict__ col,
                                                  const unsigned short* __restrict__ hIn,
                                                  const unsigned short* __restrict__ wbF,
                                                  const float* __restrict__ bias,
                                                  unsigned short* __restrict__ hOut) {
  __shared__ uint4 As[2048];  // 32 KB: 8 waves x 16 rows x 16 chunks
  const int t = threadIdx.x;
  const int wave = t >> 6, lane = t & 63;
  const int wrow0 = blockIdx.x * 128 + wave * 16;
  const int sub = lane >> 4, li = lane & 15;

  // ---- Phase 1: gather agg rows (verbatim r7 k_agg inner loop per row) ----
  for (int ri = 0; ri < 16; ri++) {
    int node = wrow0 + ri;
    float p[8];
#pragma unroll
    for (int j = 0; j < 8; j++) p[j] = 0.f;
    if (node < N_NODES) {
      int s0 = rowptr[node], s1 = rowptr[node + 1];
      int e = s0;
      for (; e + 16 <= s1; e += 16) {
        int c0 = col[e + sub];
        int c1 = col[e + 4 + sub];
        int c2 = col[e + 8 + sub];
        int c3 = col[e + 12 + sub];
        uint4 v0 = *(const uint4*)(hIn + (size_t)c0 * DIM + li * 8);
        uint4 v1 = *(const uint4*)(hIn + (size_t)c1 * DIM + li * 8);
        uint4 v2 = *(const uint4*)(hIn + (size_t)c2 * DIM + li * 8);
        uint4 v3 = *(const uint4*)(hIn + (size_t)c3 * DIM + li * 8);
        accum8(p, v0);
        accum8(p, v1);
        accum8(p, v2);
        accum8(p, v3);
      }
      if (e + 8 <= s1) {
        int c0 = col[e + sub];
        int c1 = col[e + 4 + sub];
        uint4 v0 = *(const uint4*)(hIn + (size_t)c0 * DIM + li * 8);
        uint4 v1 = *(const uint4*)(hIn + (size_t)c1 * DIM + li * 8);
        accum8(p, v0);
        accum8(p, v1);
        e += 8;
      }
      if (e + 4 <= s1) {
        int c0 = col[e + sub];
        uint4 v0 = *(const uint4*)(hIn + (size_t)c0 * DIM + li * 8);
        accum8(p, v0);
        e += 4;
      }
      if (e + sub < s1) {
        int c0 = col[e + sub];
        uint4 v0 = *(const uint4*)(hIn + (size_t)c0 * DIM + li * 8);
        accum8(p, v0);
      }
    }
#pragma unroll
    for (int j = 0; j < 8; j++) {
      p[j] += __shfl_xor(p[j], 16, 64);
      p[j] += __shfl_xor(p[j], 32, 64);
    }
    if (sub == 0) {
      uint4 o;
      o.x = (unsigned)f2bf(p[0]) | ((unsigned)f2bf(p[1]) << 16);
      o.y = (unsigned)f2bf(p[2]) | ((unsigned)f2bf(p[3]) << 16);
      o.z = (unsigned)f2bf(p[4]) | ((unsigned)f2bf(p[5]) << 16);
      o.w = (unsigned)f2bf(p[6]) | ((unsigned)f2bf(p[7]) << 16);
      As[(wave * 16 + li) * 16 + (ri ^ li)] = o;
    }
  }
  __syncthreads();

  float4v acc[8];
#pragma unroll
  for (int c2 = 0; c2 < 8; c2++)
#pragma unroll
    for (int i = 0; i < 4; i++) acc[c2][i] = 0.f;

  // ---- Phase 2a: agg @ Wrel (wbF kc 0..3) ----
#pragma unroll
  for (int kc = 0; kc < 4; kc++) {
    int c = kc * 4 + sub;
    short8v afr = *(const short8v*)&As[(wave * 16 + c) * 16 + (li ^ c)];
#pragma unroll
    for (int c2 = 0; c2 < 8; c2++) {
      short8v bfr = *(const short8v*)(wbF + (size_t)((kc * 8 + c2) * 64 + lane) * 8);
      acc[c2] = __builtin_amdgcn_mfma_f32_16x16x32_bf16(afr, bfr, acc[c2], 0, 0, 0);
    }
  }
  __syncthreads();

  // ---- restage own 16 h rows into same LDS slice ----
#pragma unroll
  for (int j = 0; j < 4; j++) {
    int idx = j * 64 + lane;
    int r = idx >> 4, c = idx & 15;
    int rsrc = wrow0 + r; if (rsrc > N_NODES - 1) rsrc = N_NODES - 1;
    uint4 v = *(const uint4*)(hIn + (size_t)rsrc * DIM + c * 8);
    As[(wave * 16 + c) * 16 + (r ^ c)] = v;
  }
  __syncthreads();

  // ---- Phase 2b: h @ Wroot (wbF kc 4..7) ----
#pragma unroll
  for (int kc = 0; kc < 4; kc++) {
    int c = kc * 4 + sub;
    short8v afr = *(const short8v*)&As[(wave * 16 + c) * 16 + (li ^ c)];
#pragma unroll
    for (int c2 = 0; c2 < 8; c2++) {
      short8v bfr = *(const short8v*)(wbF + (size_t)(((4 + kc) * 8 + c2) * 64 + lane) * 8);
      acc[c2] = __builtin_amdgcn_mfma_f32_16x16x32_bf16(afr, bfr, acc[c2], 0, 0, 0);
    }
  }

  // ---- epilogue: D layout col = lane&15, row = (lane>>4)*4 + i ----
  int rbase = wrow0 + sub * 4;
#pragma unroll
  for (int c2 = 0; c2 < 8; c2++) {
    int colidx = c2 * 16 + li;
    float bv = bias[colidx];
#pragma unroll
    for (int i = 0; i < 4; i++) {
      int row = rbase + i;
      if (row < N_NODES) {
        float v = acc[c2][i] + bv;
        v = v > 0.f ? v : 0.f;
        hOut[row * DIM + colidx] = f2bf(v);
      }
    }
  }
}

// ---------------- pooling: one wave per graph, flat uint4 streaming, no atomics ----------------
__global__ __launch_bounds__(256) void k_pool(const unsigned short* __restrict__ h,
                                              const int* __restrict__ gptr,
                                              float* __restrict__ pooledMean) {
  int g = blockIdx.x * 4 + (threadIdx.x >> 6);
  if (g >= N_GRAPHS) return;
  int lane = threadIdx.x & 63;
  int li = lane & 15;
  int s0 = gptr[g], s1 = gptr[g + 1];
  float p[8];
#pragma unroll
  for (int j = 0; j < 8; j++) p[j] = 0.f;
  int f1 = s1 * 16;
  for (int f = s0 * 16 + lane; f < f1; f += 64) {
    uint4 v = ((const uint4*)h)[f];
    accum8(p, v);
  }
#pragma unroll
  for (int j = 0; j < 8; j++) {
    p[j] += __shfl_xor(p[j], 16, 64);
    p[j] += __shfl_xor(p[j], 32, 64);
  }
  float inv = (s1 > s0) ? 1.f / (float)(s1 - s0) : 0.f;
  if (lane < 16) {
    float4 o0 = make_float4(p[0] * inv, p[1] * inv, p[2] * inv, p[3] * inv);
    float4 o1 = make_float4(p[4] * inv, p[5] * inv, p[6] * inv, p[7] * inv);
    *(float4*)(pooledMean + g * DIM + li * 8) = o0;
    *(float4*)(pooledMean + g * DIM + li * 8 + 4) = o1;
  }
}

// ---------------- fused FC head ----------------
__global__ __launch_bounds__(256) void k_fc(const float* __restrict__ pooledMean,
                                            const float* __restrict__ fc_w, const float* __restrict__ fc_b,
                                            const float* __restrict__ reg_w, const float* __restrict__ reg_b,
                                            float* __restrict__ out) {
  __shared__ float sp[128];
  __shared__ float shfc[256];
  __shared__ float red[64];
  int g = blockIdx.x, t = threadIdx.x;
  if (t < 128) sp[t] = pooledMean[g * DIM + t];
  __syncthreads();
  float a = fc_b[t];
  for (int k = 0; k < 128; k++) a += sp[k] * fc_w[k * 256 + t];
  shfc[t] = a;
  __syncthreads();
  if (t < 64) {
    int o = t & 7, seg = t >> 3;
    float r = 0.f;
    for (int j = seg * 32; j < seg * 32 + 32; j++) r += shfc[j] * reg_w[j * 8 + o];
    red[t] = r;
  }
  __syncthreads();
  if (t < 8) {
    float r = reg_b[t];
    for (int s = 0; s < 8; s++) r += red[s * 8 + t];
    out[g * 8 + t] = r;
  }
}

extern "C" void kernel_launch(void* const* d_in, const int* in_sizes, int n_in,
                              void* d_out, int out_size, void* d_ws, size_t ws_size,
                              hipStream_t stream) {
  (void)in_sizes; (void)n_in; (void)out_size; (void)ws_size;
  const float* x = (const float*)d_in[0];
  const int* ei = (const int*)d_in[1];
  const int* src = ei;
  const int* dst = ei + N_EDGES;
  const int* batch = (const int*)d_in[2];
  const float* Wrel[4]  = {(const float*)d_in[3], (const float*)d_in[6], (const float*)d_in[9],  (const float*)d_in[12]};
  const float* Wroot[4] = {(const float*)d_in[4], (const float*)d_in[7], (const float*)d_in[10], (const float*)d_in[13]};
  const float* bias[4]  = {(const float*)d_in[5], (const float*)d_in[8], (const float*)d_in[11], (const float*)d_in[14]};
  const float* fc_w  = (const float*)d_in[15];
  const float* fc_b  = (const float*)d_in[16];
  const float* reg_w = (const float*)d_in[17];
  const float* reg_b = (const float*)d_in[18];
  float* out = (float*)d_out;

  char* ws = (char*)d_ws;
  size_t off = 0;
  auto alloc = [&](size_t b) -> char* {
    char* p = ws + off;
    off = (off + b + 255) & ~(size_t)255;
    return p;
  };
  int* rowptr = (int*)alloc((N_NODES + 1) * 4);
  int* cntmat = (int*)alloc((size_t)NMAT * 4);
  int* tmpB   = (int*)alloc((size_t)NMAT * 4);
  int* bsumB  = (int*)alloc(128 * 4);
  int* base   = (int*)alloc((size_t)NMAT * 4);
  int2* epk   = (int2*)alloc((size_t)N_EDGES * 8);
  int* colws  = (int*)alloc((size_t)N_EDGES * 4);
  int* gptr   = (int*)alloc((N_GRAPHS + 1) * 4);
  unsigned short* wbF = (unsigned short*)alloc((size_t)4 * 32768 * 2);
  unsigned short* h_a = (unsigned short*)alloc((size_t)N_NODES * DIM * 2);
  unsigned short* h_b = (unsigned short*)alloc((size_t)N_NODES * DIM * 2);
  float* pooled = (float*)alloc((size_t)N_GRAPHS * DIM * 4);

  // bucket CSR build: zero global atomics
  k_bcount<<<NCH, 256, 0, stream>>>(dst, cntmat);
  k_scan1g<<<NMAT / 1024, 256, 0, stream>>>(cntmat, NMAT, tmpB, bsumB);   // 49 blocks
  k_scan2g<<<1, 128, 0, stream>>>(bsumB, NMAT / 1024);
  k_exc<<<(NMAT + 255) / 256, 256, 0, stream>>>(tmpB, bsumB, cntmat, NMAT, base);
  k_bscatter<<<NCH, 256, 0, stream>>>(src, dst, base, epk);
  k_bfinish<<<NBUK, 256, 0, stream>>>(epk, base, rowptr, colws);

  k_gptr<<<(N_NODES + 255) / 256, 256, 0, stream>>>(batch, gptr);
  k_cvtx<<<(N_NODES * DIM / 4 + 255) / 256, 256, 0, stream>>>(x, h_a);
  k_cvtw<<<(4 * 32768 + 255) / 256, 256, 0, stream>>>(
      Wrel[0], Wroot[0], Wrel[1], Wroot[1], Wrel[2], Wroot[2], Wrel[3], Wroot[3], wbF);

  unsigned short* h_in = h_a;
  unsigned short* h_out = h_b;
  const int FB = (N_NODES + 127) / 128;  // 782
  for (int l = 0; l < 4; l++) {
    k_fused<<<FB, 512, 0, stream>>>(rowptr, colws, h_in, wbF + (size_t)l * 32768, bias[l], h_out);
    unsigned short* t2 = h_in; h_in = h_out; h_out = t2;
  }
  // after 4 swaps, final features are in h_in (== h_a)

  k_pool<<<(N_GRAPHS + 3) / 4, 256, 0, stream>>>(h_in, gptr, pooled);
  k_fc<<<N_GRAPHS, 256, 0, stream>>>(pooled, fc_w, fc_b, reg_w, reg_b, out);
}

// Round 11
// 516.728 us; speedup vs baseline: 1.2047x; 1.2047x over previous
//
#include <hip/hip_runtime.h>

#define N_NODES 100000
#define N_EDGES 1600000
#define N_GRAPHS 2048
#define DIM 128

// bucket CSR build params
#define NBUK 196      // ceil(100000/512)
#define BUKSH 9       // bucket = dst >> 9 (512 nodes per bucket)
#define NCH 256       // edge chunks (blocks) in passes A/C
#define EPB 6250      // edges per chunk = N_EDGES / NCH
#define NMAT (NBUK * NCH)  // 50176

typedef short short8v __attribute__((ext_vector_type(8)));
typedef float float4v __attribute__((ext_vector_type(4)));

__device__ __forceinline__ unsigned short f2bf(float f) {
  union { float f; unsigned u; } x; x.f = f;
  unsigned r = x.u + 0x7fffu + ((x.u >> 16) & 1u);
  return (unsigned short)(r >> 16);
}
__device__ __forceinline__ float bfhi2f(unsigned bits) {  // bits already in high half
  union { unsigned u; float f; } x; x.u = bits; return x.f;
}
__device__ __forceinline__ void accum8(float* p, uint4 v) {
  p[0] += bfhi2f(v.x << 16); p[1] += bfhi2f(v.x & 0xffff0000u);
  p[2] += bfhi2f(v.y << 16); p[3] += bfhi2f(v.y & 0xffff0000u);
  p[4] += bfhi2f(v.z << 16); p[5] += bfhi2f(v.z & 0xffff0000u);
  p[6] += bfhi2f(v.w << 16); p[7] += bfhi2f(v.w & 0xffff0000u);
}

// ---------------- bucket CSR build (zero global atomics) ----------------
__global__ __launch_bounds__(256) void k_bcount(const int* __restrict__ dst, int* __restrict__ cntmat) {
  __shared__ int cnt[NBUK];
  int b = blockIdx.x, t = threadIdx.x;
  if (t < NBUK) cnt[t] = 0;
  __syncthreads();
  int e0 = b * EPB;
  for (int j = t; j < EPB; j += 256) atomicAdd(&cnt[dst[e0 + j] >> BUKSH], 1);
  __syncthreads();
  if (t < NBUK) cntmat[t * NCH + b] = cnt[t];
}

// generic scan (chunk = 1024/block)
__global__ __launch_bounds__(256) void k_scan1g(const int* __restrict__ in, int n,
                                                int* __restrict__ tmp, int* __restrict__ bsum) {
  __shared__ int sh[256];
  int b = blockIdx.x, t = threadIdx.x;
  int base = b * 1024 + t * 4;
  int v[4], s = 0;
#pragma unroll
  for (int i = 0; i < 4; i++) { v[i] = (base + i < n) ? in[base + i] : 0; s += v[i]; }
  sh[t] = s;
  __syncthreads();
  for (int off = 1; off < 256; off <<= 1) {
    int x = (t >= off) ? sh[t - off] : 0;
    __syncthreads();
    sh[t] += x;
    __syncthreads();
  }
  int run = sh[t] - s;
#pragma unroll
  for (int i = 0; i < 4; i++) { run += v[i]; if (base + i < n) tmp[base + i] = run; }
  if (t == 255) bsum[b] = sh[255];
}

__global__ void k_scan2g(int* __restrict__ bsum, int nb) {
  __shared__ int sh[128];
  int t = threadIdx.x;
  int v = (t < nb) ? bsum[t] : 0;
  sh[t] = v;
  __syncthreads();
  for (int off = 1; off < 128; off <<= 1) {
    int x = (t >= off) ? sh[t - off] : 0;
    __syncthreads();
    sh[t] += x;
    __syncthreads();
  }
  if (t < nb) bsum[t] = sh[t] - v;  // exclusive
}

__global__ __launch_bounds__(256) void k_exc(const int* __restrict__ tmp, const int* __restrict__ bsum,
                                             const int* __restrict__ in, int n, int* __restrict__ outExc) {
  int i = blockIdx.x * 256 + threadIdx.x;
  if (i < n) outExc[i] = tmp[i] + bsum[i >> 10] - in[i];
}

__global__ __launch_bounds__(256) void k_bscatter(const int* __restrict__ src, const int* __restrict__ dst,
                                                  const int* __restrict__ base, int2* __restrict__ epk) {
  __shared__ int cur[NBUK];
  int b = blockIdx.x, t = threadIdx.x;
  if (t < NBUK) cur[t] = base[t * NCH + b];
  __syncthreads();
  int e0 = b * EPB;
  for (int j = t; j < EPB; j += 256) {
    int s = src[e0 + j], d = dst[e0 + j];
    int pos = atomicAdd(&cur[d >> BUKSH], 1);
    epk[pos] = make_int2(s, d);
  }
}

__global__ __launch_bounds__(256) void k_bfinish(const int2* __restrict__ epk, const int* __restrict__ base,
                                                 int* __restrict__ rowptr, int* __restrict__ col) {
  __shared__ int a[512];
  __shared__ int sh[256];
  int k = blockIdx.x, t = threadIdx.x;
  int bstart = base[k * NCH];
  int bend = (k + 1 < NBUK) ? base[(k + 1) * NCH] : N_EDGES;
  a[t] = 0; a[t + 256] = 0;
  __syncthreads();
  for (int i = bstart + t; i < bend; i += 256) atomicAdd(&a[epk[i].y - (k << BUKSH)], 1);
  __syncthreads();
  int c0 = a[2 * t], c1 = a[2 * t + 1];
  int s = c0 + c1;
  sh[t] = s;
  __syncthreads();
  for (int off = 1; off < 256; off <<= 1) {
    int x = (t >= off) ? sh[t - off] : 0;
    __syncthreads();
    sh[t] += x;
    __syncthreads();
  }
  int excl = sh[t] - s;
  int st0 = bstart + excl;
  int st1 = st0 + c0;
  int g0 = (k << BUKSH) + 2 * t, g1 = g0 + 1;
  if (g0 < N_NODES) rowptr[g0] = st0;
  if (g1 < N_NODES) rowptr[g1] = st1;
  if (k == NBUK - 1 && t == 0) rowptr[N_NODES] = N_EDGES;
  __syncthreads();
  a[2 * t] = st0; a[2 * t + 1] = st1;  // convert to cursors
  __syncthreads();
  for (int i = bstart + t; i < bend; i += 256) {
    int2 e = epk[i];
    int pos = atomicAdd(&a[e.y - (k << BUKSH)], 1);
    col[pos] = e.x;
  }
}

// ---------------- graph boundary pointers (batch is sorted) ----------------
__global__ __launch_bounds__(256) void k_gptr(const int* __restrict__ batch, int* __restrict__ gptr) {
  int i = blockIdx.x * 256 + threadIdx.x;
  if (i >= N_NODES) return;
  int b = batch[i];
  int a = (i == 0) ? -1 : batch[i - 1];
  for (int g = a + 1; g <= b; g++) gptr[g] = i;
  if (i == N_NODES - 1) {
    for (int g = b + 1; g <= N_GRAPHS; g++) gptr[g] = N_NODES;
  }
}

// ---------------- dtype converts ----------------
__global__ __launch_bounds__(256) void k_cvtx(const float* __restrict__ x, unsigned short* __restrict__ h) {
  int i = blockIdx.x * 256 + threadIdx.x;  // over N*DIM/4
  if (i < N_NODES * DIM / 4) {
    float4 v = ((const float4*)x)[i];
    unsigned lo = (unsigned)f2bf(v.x) | ((unsigned)f2bf(v.y) << 16);
    unsigned hi = (unsigned)f2bf(v.z) | ((unsigned)f2bf(v.w) << 16);
    ((uint2*)h)[i] = make_uint2(lo, hi);
  }
}

// Weights -> bf16 MFMA B-fragment order.
__global__ __launch_bounds__(256) void k_cvtw(const float* w0, const float* w1, const float* w2, const float* w3,
                                              const float* w4, const float* w5, const float* w6, const float* w7,
                                              unsigned short* __restrict__ wbF) {
  int i = blockIdx.x * 256 + threadIdx.x;
  if (i < 4 * 8 * 8 * 64 * 8) {
    int j = i & 7, l = (i >> 3) & 63, c = (i >> 9) & 7, kc = (i >> 12) & 7, layer = i >> 15;
    int m = layer * 2 + (kc >> 2);
    const float* w;
    switch (m) {
      case 0: w = w0; break; case 1: w = w1; break; case 2: w = w2; break; case 3: w = w3; break;
      case 4: w = w4; break; case 5: w = w5; break; case 6: w = w6; break; default: w = w7; break;
    }
    int kin = (kc & 3) * 32 + ((l >> 4) * 8) + j;
    int n = c * 16 + (l & 15);
    wbF[i] = f2bf(w[kin * 128 + n]);
  }
}

// ---------------- fused layer: h' = relu(segsum(h)[dst] @ Wrel + h @ Wroot + b) ----------------
// 256 thr = 4 waves, 64 rows/block, 16 rows/wave, 16 KB LDS. Each wave autonomous:
//   gather agg for its 16 rows (r7 k_agg inner loop) -> own 4KB LDS slice (frag layout)
//   -> 4 kc MFMA vs Wrel -> restage its 16 h rows into same slice -> 4 kc MFMA vs Wroot.
// __launch_bounds__(256,8): 8 waves/EU -> 8 blocks/CU (LDS 16KB x 8 = 128 <= 160; VGPR <= 64).
// Grid 1563 = 6.1 blocks/CU < 8 cap -> fully resident, no tail. (r10 lesson: (512,4) capped
// occupancy at 2 blocks/CU and halved the latency-bound gather rate.)
__global__ __launch_bounds__(256, 8) void k_fused(const int* __restrict__ rowptr,
                                                  const int* __restrict__ col,
                                                  const unsigned short* __restrict__ hIn,
                                                  const unsigned short* __restrict__ wbF,
                                                  const float* __restrict__ bias,
                                                  unsigned short* __restrict__ hOut) {
  __shared__ uint4 As[1024];  // 16 KB: 4 waves x 16 rows x 16 chunks
  const int t = threadIdx.x;
  const int wave = t >> 6, lane = t & 63;
  const int wrow0 = blockIdx.x * 64 + wave * 16;
  const int sub = lane >> 4, li = lane & 15;

  // ---- Phase 1: gather agg rows (verbatim r7 k_agg inner loop per row) ----
  for (int ri = 0; ri < 16; ri++) {
    int node = wrow0 + ri;
    float p[8];
#pragma unroll
    for (int j = 0; j < 8; j++) p[j] = 0.f;
    if (node < N_NODES) {
      int s0 = rowptr[node], s1 = rowptr[node + 1];
      int e = s0;
      for (; e + 16 <= s1; e += 16) {
        int c0 = col[e + sub];
        int c1 = col[e + 4 + sub];
        int c2 = col[e + 8 + sub];
        int c3 = col[e + 12 + sub];
        uint4 v0 = *(const uint4*)(hIn + (size_t)c0 * DIM + li * 8);
        uint4 v1 = *(const uint4*)(hIn + (size_t)c1 * DIM + li * 8);
        uint4 v2 = *(const uint4*)(hIn + (size_t)c2 * DIM + li * 8);
        uint4 v3 = *(const uint4*)(hIn + (size_t)c3 * DIM + li * 8);
        accum8(p, v0);
        accum8(p, v1);
        accum8(p, v2);
        accum8(p, v3);
      }
      if (e + 8 <= s1) {
        int c0 = col[e + sub];
        int c1 = col[e + 4 + sub];
        uint4 v0 = *(const uint4*)(hIn + (size_t)c0 * DIM + li * 8);
        uint4 v1 = *(const uint4*)(hIn + (size_t)c1 * DIM + li * 8);
        accum8(p, v0);
        accum8(p, v1);
        e += 8;
      }
      if (e + 4 <= s1) {
        int c0 = col[e + sub];
        uint4 v0 = *(const uint4*)(hIn + (size_t)c0 * DIM + li * 8);
        accum8(p, v0);
        e += 4;
      }
      if (e + sub < s1) {
        int c0 = col[e + sub];
        uint4 v0 = *(const uint4*)(hIn + (size_t)c0 * DIM + li * 8);
        accum8(p, v0);
      }
    }
#pragma unroll
    for (int j = 0; j < 8; j++) {
      p[j] += __shfl_xor(p[j], 16, 64);
      p[j] += __shfl_xor(p[j], 32, 64);
    }
    if (sub == 0) {
      uint4 o;
      o.x = (unsigned)f2bf(p[0]) | ((unsigned)f2bf(p[1]) << 16);
      o.y = (unsigned)f2bf(p[2]) | ((unsigned)f2bf(p[3]) << 16);
      o.z = (unsigned)f2bf(p[4]) | ((unsigned)f2bf(p[5]) << 16);
      o.w = (unsigned)f2bf(p[6]) | ((unsigned)f2bf(p[7]) << 16);
      As[(wave * 16 + li) * 16 + (ri ^ li)] = o;
    }
  }
  __syncthreads();

  float4v acc[8];
#pragma unroll
  for (int c2 = 0; c2 < 8; c2++)
#pragma unroll
    for (int i = 0; i < 4; i++) acc[c2][i] = 0.f;

  // ---- Phase 2a: agg @ Wrel (wbF kc 0..3) ----
#pragma unroll
  for (int kc = 0; kc < 4; kc++) {
    int c = kc * 4 + sub;
    short8v afr = *(const short8v*)&As[(wave * 16 + c) * 16 + (li ^ c)];
#pragma unroll
    for (int c2 = 0; c2 < 8; c2++) {
      short8v bfr = *(const short8v*)(wbF + (size_t)((kc * 8 + c2) * 64 + lane) * 8);
      acc[c2] = __builtin_amdgcn_mfma_f32_16x16x32_bf16(afr, bfr, acc[c2], 0, 0, 0);
    }
  }
  __syncthreads();

  // ---- restage own 16 h rows into same LDS slice ----
#pragma unroll
  for (int j = 0; j < 4; j++) {
    int idx = j * 64 + lane;
    int r = idx >> 4, c = idx & 15;
    int rsrc = wrow0 + r; if (rsrc > N_NODES - 1) rsrc = N_NODES - 1;
    uint4 v = *(const uint4*)(hIn + (size_t)rsrc * DIM + c * 8);
    As[(wave * 16 + c) * 16 + (r ^ c)] = v;
  }
  __syncthreads();

  // ---- Phase 2b: h @ Wroot (wbF kc 4..7) ----
#pragma unroll
  for (int kc = 0; kc < 4; kc++) {
    int c = kc * 4 + sub;
    short8v afr = *(const short8v*)&As[(wave * 16 + c) * 16 + (li ^ c)];
#pragma unroll
    for (int c2 = 0; c2 < 8; c2++) {
      short8v bfr = *(const short8v*)(wbF + (size_t)(((4 + kc) * 8 + c2) * 64 + lane) * 8);
      acc[c2] = __builtin_amdgcn_mfma_f32_16x16x32_bf16(afr, bfr, acc[c2], 0, 0, 0);
    }
  }

  // ---- epilogue: D layout col = lane&15, row = (lane>>4)*4 + i ----
  int rbase = wrow0 + sub * 4;
#pragma unroll
  for (int c2 = 0; c2 < 8; c2++) {
    int colidx = c2 * 16 + li;
    float bv = bias[colidx];
#pragma unroll
    for (int i = 0; i < 4; i++) {
      int row = rbase + i;
      if (row < N_NODES) {
        float v = acc[c2][i] + bv;
        v = v > 0.f ? v : 0.f;
        hOut[row * DIM + colidx] = f2bf(v);
      }
    }
  }
}

// ---------------- pooling: one wave per graph, flat uint4 streaming, no atomics ----------------
__global__ __launch_bounds__(256) void k_pool(const unsigned short* __restrict__ h,
                                              const int* __restrict__ gptr,
                                              float* __restrict__ pooledMean) {
  int g = blockIdx.x * 4 + (threadIdx.x >> 6);
  if (g >= N_GRAPHS) return;
  int lane = threadIdx.x & 63;
  int li = lane & 15;
  int s0 = gptr[g], s1 = gptr[g + 1];
  float p[8];
#pragma unroll
  for (int j = 0; j < 8; j++) p[j] = 0.f;
  int f1 = s1 * 16;
  for (int f = s0 * 16 + lane; f < f1; f += 64) {
    uint4 v = ((const uint4*)h)[f];
    accum8(p, v);
  }
#pragma unroll
  for (int j = 0; j < 8; j++) {
    p[j] += __shfl_xor(p[j], 16, 64);
    p[j] += __shfl_xor(p[j], 32, 64);
  }
  float inv = (s1 > s0) ? 1.f / (float)(s1 - s0) : 0.f;
  if (lane < 16) {
    float4 o0 = make_float4(p[0] * inv, p[1] * inv, p[2] * inv, p[3] * inv);
    float4 o1 = make_float4(p[4] * inv, p[5] * inv, p[6] * inv, p[7] * inv);
    *(float4*)(pooledMean + g * DIM + li * 8) = o0;
    *(float4*)(pooledMean + g * DIM + li * 8 + 4) = o1;
  }
}

// ---------------- fused FC head ----------------
__global__ __launch_bounds__(256) void k_fc(const float* __restrict__ pooledMean,
                                            const float* __restrict__ fc_w, const float* __restrict__ fc_b,
                                            const float* __restrict__ reg_w, const float* __restrict__ reg_b,
                                            float* __restrict__ out) {
  __shared__ float sp[128];
  __shared__ float shfc[256];
  __shared__ float red[64];
  int g = blockIdx.x, t = threadIdx.x;
  if (t < 128) sp[t] = pooledMean[g * DIM + t];
  __syncthreads();
  float a = fc_b[t];
  for (int k = 0; k < 128; k++) a += sp[k] * fc_w[k * 256 + t];
  shfc[t] = a;
  __syncthreads();
  if (t < 64) {
    int o = t & 7, seg = t >> 3;
    float r = 0.f;
    for (int j = seg * 32; j < seg * 32 + 32; j++) r += shfc[j] * reg_w[j * 8 + o];
    red[t] = r;
  }
  __syncthreads();
  if (t < 8) {
    float r = reg_b[t];
    for (int s = 0; s < 8; s++) r += red[s * 8 + t];
    out[g * 8 + t] = r;
  }
}

extern "C" void kernel_launch(void* const* d_in, const int* in_sizes, int n_in,
                              void* d_out, int out_size, void* d_ws, size_t ws_size,
                              hipStream_t stream) {
  (void)in_sizes; (void)n_in; (void)out_size; (void)ws_size;
  const float* x = (const float*)d_in[0];
  const int* ei = (const int*)d_in[1];
  const int* src = ei;
  const int* dst = ei + N_EDGES;
  const int* batch = (const int*)d_in[2];
  const float* Wrel[4]  = {(const float*)d_in[3], (const float*)d_in[6], (const float*)d_in[9],  (const float*)d_in[12]};
  const float* Wroot[4] = {(const float*)d_in[4], (const float*)d_in[7], (const float*)d_in[10], (const float*)d_in[13]};
  const float* bias[4]  = {(const float*)d_in[5], (const float*)d_in[8], (const float*)d_in[11], (const float*)d_in[14]};
  const float* fc_w  = (const float*)d_in[15];
  const float* fc_b  = (const float*)d_in[16];
  const float* reg_w = (const float*)d_in[17];
  const float* reg_b = (const float*)d_in[18];
  float* out = (float*)d_out;

  char* ws = (char*)d_ws;
  size_t off = 0;
  auto alloc = [&](size_t b) -> char* {
    char* p = ws + off;
    off = (off + b + 255) & ~(size_t)255;
    return p;
  };
  int* rowptr = (int*)alloc((N_NODES + 1) * 4);
  int* cntmat = (int*)alloc((size_t)NMAT * 4);
  int* tmpB   = (int*)alloc((size_t)NMAT * 4);
  int* bsumB  = (int*)alloc(128 * 4);
  int* base   = (int*)alloc((size_t)NMAT * 4);
  int2* epk   = (int2*)alloc((size_t)N_EDGES * 8);
  int* colws  = (int*)alloc((size_t)N_EDGES * 4);
  int* gptr   = (int*)alloc((N_GRAPHS + 1) * 4);
  unsigned short* wbF = (unsigned short*)alloc((size_t)4 * 32768 * 2);
  unsigned short* h_a = (unsigned short*)alloc((size_t)N_NODES * DIM * 2);
  unsigned short* h_b = (unsigned short*)alloc((size_t)N_NODES * DIM * 2);
  float* pooled = (float*)alloc((size_t)N_GRAPHS * DIM * 4);

  // bucket CSR build: zero global atomics
  k_bcount<<<NCH, 256, 0, stream>>>(dst, cntmat);
  k_scan1g<<<NMAT / 1024, 256, 0, stream>>>(cntmat, NMAT, tmpB, bsumB);   // 49 blocks
  k_scan2g<<<1, 128, 0, stream>>>(bsumB, NMAT / 1024);
  k_exc<<<(NMAT + 255) / 256, 256, 0, stream>>>(tmpB, bsumB, cntmat, NMAT, base);
  k_bscatter<<<NCH, 256, 0, stream>>>(src, dst, base, epk);
  k_bfinish<<<NBUK, 256, 0, stream>>>(epk, base, rowptr, colws);

  k_gptr<<<(N_NODES + 255) / 256, 256, 0, stream>>>(batch, gptr);
  k_cvtx<<<(N_NODES * DIM / 4 + 255) / 256, 256, 0, stream>>>(x, h_a);
  k_cvtw<<<(4 * 32768 + 255) / 256, 256, 0, stream>>>(
      Wrel[0], Wroot[0], Wrel[1], Wroot[1], Wrel[2], Wroot[2], Wrel[3], Wroot[3], wbF);

  unsigned short* h_in = h_a;
  unsigned short* h_out = h_b;
  const int FB = (N_NODES + 63) / 64;  // 1563 blocks, 6.1/CU < 8 cap -> fully resident
  for (int l = 0; l < 4; l++) {
    k_fused<<<FB, 256, 0, stream>>>(rowptr, colws, h_in, wbF + (size_t)l * 32768, bias[l], h_out);
    unsigned short* t2 = h_in; h_in = h_out; h_out = t2;
  }
  // after 4 swaps, final features are in h_in (== h_a)

  k_pool<<<(N_GRAPHS + 3) / 4, 256, 0, stream>>>(h_in, gptr, pooled);
  k_fc<<<N_GRAPHS, 256, 0, stream>>>(pooled, fc_w, fc_b, reg_w, reg_b, out);
}

// Round 12
// 509.714 us; speedup vs baseline: 1.2212x; 1.0138x over previous
//
#include <hip/hip_runtime.h>

#define N_NODES 100000
#define N_EDGES 1600000
#define N_GRAPHS 2048
#define DIM 128

// bucket CSR build params
#define NBUK 196      // ceil(100000/512)
#define BUKSH 9       // bucket = dst >> 9 (512 nodes per bucket)
#define NCH 256       // edge chunks (blocks) in passes A/C
#define EPB 6250      // edges per chunk = N_EDGES / NCH
#define NMAT (NBUK * NCH)  // 50176

typedef short short8v __attribute__((ext_vector_type(8)));
typedef float float4v __attribute__((ext_vector_type(4)));

__device__ __forceinline__ unsigned short f2bf(float f) {
  union { float f; unsigned u; } x; x.f = f;
  unsigned r = x.u + 0x7fffu + ((x.u >> 16) & 1u);
  return (unsigned short)(r >> 16);
}
__device__ __forceinline__ float bfhi2f(unsigned bits) {  // bits already in high half
  union { unsigned u; float f; } x; x.u = bits; return x.f;
}
__device__ __forceinline__ void accum8(float* p, uint4 v) {
  p[0] += bfhi2f(v.x << 16); p[1] += bfhi2f(v.x & 0xffff0000u);
  p[2] += bfhi2f(v.y << 16); p[3] += bfhi2f(v.y & 0xffff0000u);
  p[4] += bfhi2f(v.z << 16); p[5] += bfhi2f(v.z & 0xffff0000u);
  p[6] += bfhi2f(v.w << 16); p[7] += bfhi2f(v.w & 0xffff0000u);
}

// ---------------- bucket CSR build (zero global atomics) ----------------
__global__ __launch_bounds__(256) void k_bcount(const int* __restrict__ dst, int* __restrict__ cntmat) {
  __shared__ int cnt[NBUK];
  int b = blockIdx.x, t = threadIdx.x;
  if (t < NBUK) cnt[t] = 0;
  __syncthreads();
  int e0 = b * EPB;
  for (int j = t; j < EPB; j += 256) atomicAdd(&cnt[dst[e0 + j] >> BUKSH], 1);
  __syncthreads();
  if (t < NBUK) cntmat[t * NCH + b] = cnt[t];
}

// generic scan (chunk = 1024/block)
__global__ __launch_bounds__(256) void k_scan1g(const int* __restrict__ in, int n,
                                                int* __restrict__ tmp, int* __restrict__ bsum) {
  __shared__ int sh[256];
  int b = blockIdx.x, t = threadIdx.x;
  int base = b * 1024 + t * 4;
  int v[4], s = 0;
#pragma unroll
  for (int i = 0; i < 4; i++) { v[i] = (base + i < n) ? in[base + i] : 0; s += v[i]; }
  sh[t] = s;
  __syncthreads();
  for (int off = 1; off < 256; off <<= 1) {
    int x = (t >= off) ? sh[t - off] : 0;
    __syncthreads();
    sh[t] += x;
    __syncthreads();
  }
  int run = sh[t] - s;
#pragma unroll
  for (int i = 0; i < 4; i++) { run += v[i]; if (base + i < n) tmp[base + i] = run; }
  if (t == 255) bsum[b] = sh[255];
}

__global__ void k_scan2g(int* __restrict__ bsum, int nb) {
  __shared__ int sh[128];
  int t = threadIdx.x;
  int v = (t < nb) ? bsum[t] : 0;
  sh[t] = v;
  __syncthreads();
  for (int off = 1; off < 128; off <<= 1) {
    int x = (t >= off) ? sh[t - off] : 0;
    __syncthreads();
    sh[t] += x;
    __syncthreads();
  }
  if (t < nb) bsum[t] = sh[t] - v;  // exclusive
}

__global__ __launch_bounds__(256) void k_exc(const int* __restrict__ tmp, const int* __restrict__ bsum,
                                             const int* __restrict__ in, int n, int* __restrict__ outExc) {
  int i = blockIdx.x * 256 + threadIdx.x;
  if (i < n) outExc[i] = tmp[i] + bsum[i >> 10] - in[i];
}

__global__ __launch_bounds__(256) void k_bscatter(const int* __restrict__ src, const int* __restrict__ dst,
                                                  const int* __restrict__ base, int2* __restrict__ epk) {
  __shared__ int cur[NBUK];
  int b = blockIdx.x, t = threadIdx.x;
  if (t < NBUK) cur[t] = base[t * NCH + b];
  __syncthreads();
  int e0 = b * EPB;
  for (int j = t; j < EPB; j += 256) {
    int s = src[e0 + j], d = dst[e0 + j];
    int pos = atomicAdd(&cur[d >> BUKSH], 1);
    epk[pos] = make_int2(s, d);
  }
}

__global__ __launch_bounds__(256) void k_bfinish(const int2* __restrict__ epk, const int* __restrict__ base,
                                                 int* __restrict__ rowptr, int* __restrict__ col) {
  __shared__ int a[512];
  __shared__ int sh[256];
  int k = blockIdx.x, t = threadIdx.x;
  int bstart = base[k * NCH];
  int bend = (k + 1 < NBUK) ? base[(k + 1) * NCH] : N_EDGES;
  a[t] = 0; a[t + 256] = 0;
  __syncthreads();
  for (int i = bstart + t; i < bend; i += 256) atomicAdd(&a[epk[i].y - (k << BUKSH)], 1);
  __syncthreads();
  int c0 = a[2 * t], c1 = a[2 * t + 1];
  int s = c0 + c1;
  sh[t] = s;
  __syncthreads();
  for (int off = 1; off < 256; off <<= 1) {
    int x = (t >= off) ? sh[t - off] : 0;
    __syncthreads();
    sh[t] += x;
    __syncthreads();
  }
  int excl = sh[t] - s;
  int st0 = bstart + excl;
  int st1 = st0 + c0;
  int g0 = (k << BUKSH) + 2 * t, g1 = g0 + 1;
  if (g0 < N_NODES) rowptr[g0] = st0;
  if (g1 < N_NODES) rowptr[g1] = st1;
  if (k == NBUK - 1 && t == 0) rowptr[N_NODES] = N_EDGES;
  __syncthreads();
  a[2 * t] = st0; a[2 * t + 1] = st1;  // convert to cursors
  __syncthreads();
  for (int i = bstart + t; i < bend; i += 256) {
    int2 e = epk[i];
    int pos = atomicAdd(&a[e.y - (k << BUKSH)], 1);
    col[pos] = e.x;
  }
}

// ---------------- graph boundary pointers (batch is sorted) ----------------
__global__ __launch_bounds__(256) void k_gptr(const int* __restrict__ batch, int* __restrict__ gptr) {
  int i = blockIdx.x * 256 + threadIdx.x;
  if (i >= N_NODES) return;
  int b = batch[i];
  int a = (i == 0) ? -1 : batch[i - 1];
  for (int g = a + 1; g <= b; g++) gptr[g] = i;
  if (i == N_NODES - 1) {
    for (int g = b + 1; g <= N_GRAPHS; g++) gptr[g] = N_NODES;
  }
}

// ---------------- dtype converts ----------------
__global__ __launch_bounds__(256) void k_cvtx(const float* __restrict__ x, unsigned short* __restrict__ h) {
  int i = blockIdx.x * 256 + threadIdx.x;  // over N*DIM/4
  if (i < N_NODES * DIM / 4) {
    float4 v = ((const float4*)x)[i];
    unsigned lo = (unsigned)f2bf(v.x) | ((unsigned)f2bf(v.y) << 16);
    unsigned hi = (unsigned)f2bf(v.z) | ((unsigned)f2bf(v.w) << 16);
    ((uint2*)h)[i] = make_uint2(lo, hi);
  }
}

// Weights -> bf16 MFMA B-fragment order.
__global__ __launch_bounds__(256) void k_cvtw(const float* w0, const float* w1, const float* w2, const float* w3,
                                              const float* w4, const float* w5, const float* w6, const float* w7,
                                              unsigned short* __restrict__ wbF) {
  int i = blockIdx.x * 256 + threadIdx.x;
  if (i < 4 * 8 * 8 * 64 * 8) {
    int j = i & 7, l = (i >> 3) & 63, c = (i >> 9) & 7, kc = (i >> 12) & 7, layer = i >> 15;
    int m = layer * 2 + (kc >> 2);
    const float* w;
    switch (m) {
      case 0: w = w0; break; case 1: w = w1; break; case 2: w = w2; break; case 3: w = w3; break;
      case 4: w = w4; break; case 5: w = w5; break; case 6: w = w6; break; default: w = w7; break;
    }
    int kin = (kc & 3) * 32 + ((l >> 4) * 8) + j;
    int n = c * 16 + (l & 15);
    wbF[i] = f2bf(w[kin * 128 + n]);
  }
}

// ---------------- fused layer: h' = relu(segsum(h)[dst] @ Wrel + h @ Wroot + b) ----------------
// 256 thr = 4 waves, 64 rows/block, 16 rows/wave, 16 KB LDS. Waves fully autonomous:
// each wave reads ONLY the LDS slice it wrote itself -> NO __syncthreads anywhere
// (within-wave ds ordering handled by lgkmcnt). Gather is pair-interleaved: rows A,B
// processed jointly (2 dwordx4 per row in flight) so row latencies overlap; per-row
// accumulation order is unchanged (ascending e, e+4, ...) -> bit-identical to r11.
__global__ __launch_bounds__(256, 8) void k_fused(const int* __restrict__ rowptr,
                                                  const int* __restrict__ col,
                                                  const unsigned short* __restrict__ hIn,
                                                  const unsigned short* __restrict__ wbF,
                                                  const float* __restrict__ bias,
                                                  unsigned short* __restrict__ hOut) {
  __shared__ uint4 As[1024];  // 16 KB: 4 waves x 16 rows x 16 chunks
  const int t = threadIdx.x;
  const int wave = t >> 6, lane = t & 63;
  const int wrow0 = blockIdx.x * 64 + wave * 16;
  const int sub = lane >> 4, li = lane & 15;

  // ---- Phase 1: pair-interleaved gather of 16 rows ----
  for (int ri = 0; ri < 16; ri += 2) {
    int nodeA = wrow0 + ri;
    int nodeB = nodeA + 1;
    float pA[8], pB[8];
#pragma unroll
    for (int j = 0; j < 8; j++) { pA[j] = 0.f; pB[j] = 0.f; }
    int aS1 = 0, bS1 = 0, eA = 0, eB = 0;
    if (nodeA < N_NODES) { eA = rowptr[nodeA]; aS1 = rowptr[nodeA + 1]; }
    if (nodeB < N_NODES) { eB = rowptr[nodeB]; bS1 = rowptr[nodeB + 1]; }

    // joint loop: 8 edges per row per iter, A/B latencies overlap
    while (eA + 8 <= aS1 && eB + 8 <= bS1) {
      int cA0 = col[eA + sub], cA1 = col[eA + 4 + sub];
      int cB0 = col[eB + sub], cB1 = col[eB + 4 + sub];
      uint4 vA0 = *(const uint4*)(hIn + (size_t)cA0 * DIM + li * 8);
      uint4 vA1 = *(const uint4*)(hIn + (size_t)cA1 * DIM + li * 8);
      uint4 vB0 = *(const uint4*)(hIn + (size_t)cB0 * DIM + li * 8);
      uint4 vB1 = *(const uint4*)(hIn + (size_t)cB1 * DIM + li * 8);
      accum8(pA, vA0);
      accum8(pA, vA1);
      accum8(pB, vB0);
      accum8(pB, vB1);
      eA += 8; eB += 8;
    }
    // drain A (r7 chunk order: x16 / x8 / x4 / rem)
    for (; eA + 16 <= aS1; eA += 16) {
      int c0 = col[eA + sub], c1 = col[eA + 4 + sub], c2 = col[eA + 8 + sub], c3 = col[eA + 12 + sub];
      uint4 v0 = *(const uint4*)(hIn + (size_t)c0 * DIM + li * 8);
      uint4 v1 = *(const uint4*)(hIn + (size_t)c1 * DIM + li * 8);
      uint4 v2 = *(const uint4*)(hIn + (size_t)c2 * DIM + li * 8);
      uint4 v3 = *(const uint4*)(hIn + (size_t)c3 * DIM + li * 8);
      accum8(pA, v0); accum8(pA, v1); accum8(pA, v2); accum8(pA, v3);
    }
    if (eA + 8 <= aS1) {
      int c0 = col[eA + sub], c1 = col[eA + 4 + sub];
      uint4 v0 = *(const uint4*)(hIn + (size_t)c0 * DIM + li * 8);
      uint4 v1 = *(const uint4*)(hIn + (size_t)c1 * DIM + li * 8);
      accum8(pA, v0); accum8(pA, v1);
      eA += 8;
    }
    if (eA + 4 <= aS1) {
      int c0 = col[eA + sub];
      uint4 v0 = *(const uint4*)(hIn + (size_t)c0 * DIM + li * 8);
      accum8(pA, v0);
      eA += 4;
    }
    if (eA + sub < aS1) {
      int c0 = col[eA + sub];
      uint4 v0 = *(const uint4*)(hIn + (size_t)c0 * DIM + li * 8);
      accum8(pA, v0);
    }
    // drain B
    for (; eB + 16 <= bS1; eB += 16) {
      int c0 = col[eB + sub], c1 = col[eB + 4 + sub], c2 = col[eB + 8 + sub], c3 = col[eB + 12 + sub];
      uint4 v0 = *(const uint4*)(hIn + (size_t)c0 * DIM + li * 8);
      uint4 v1 = *(const uint4*)(hIn + (size_t)c1 * DIM + li * 8);
      uint4 v2 = *(const uint4*)(hIn + (size_t)c2 * DIM + li * 8);
      uint4 v3 = *(const uint4*)(hIn + (size_t)c3 * DIM + li * 8);
      accum8(pB, v0); accum8(pB, v1); accum8(pB, v2); accum8(pB, v3);
    }
    if (eB + 8 <= bS1) {
      int c0 = col[eB + sub], c1 = col[eB + 4 + sub];
      uint4 v0 = *(const uint4*)(hIn + (size_t)c0 * DIM + li * 8);
      uint4 v1 = *(const uint4*)(hIn + (size_t)c1 * DIM + li * 8);
      accum8(pB, v0); accum8(pB, v1);
      eB += 8;
    }
    if (eB + 4 <= bS1) {
      int c0 = col[eB + sub];
      uint4 v0 = *(const uint4*)(hIn + (size_t)c0 * DIM + li * 8);
      accum8(pB, v0);
      eB += 4;
    }
    if (eB + sub < bS1) {
      int c0 = col[eB + sub];
      uint4 v0 = *(const uint4*)(hIn + (size_t)c0 * DIM + li * 8);
      accum8(pB, v0);
    }

#pragma unroll
    for (int j = 0; j < 8; j++) {
      pA[j] += __shfl_xor(pA[j], 16, 64);
      pA[j] += __shfl_xor(pA[j], 32, 64);
      pB[j] += __shfl_xor(pB[j], 16, 64);
      pB[j] += __shfl_xor(pB[j], 32, 64);
    }
    if (sub == 0) {
      uint4 oA, oB;
      oA.x = (unsigned)f2bf(pA[0]) | ((unsigned)f2bf(pA[1]) << 16);
      oA.y = (unsigned)f2bf(pA[2]) | ((unsigned)f2bf(pA[3]) << 16);
      oA.z = (unsigned)f2bf(pA[4]) | ((unsigned)f2bf(pA[5]) << 16);
      oA.w = (unsigned)f2bf(pA[6]) | ((unsigned)f2bf(pA[7]) << 16);
      oB.x = (unsigned)f2bf(pB[0]) | ((unsigned)f2bf(pB[1]) << 16);
      oB.y = (unsigned)f2bf(pB[2]) | ((unsigned)f2bf(pB[3]) << 16);
      oB.z = (unsigned)f2bf(pB[4]) | ((unsigned)f2bf(pB[5]) << 16);
      oB.w = (unsigned)f2bf(pB[6]) | ((unsigned)f2bf(pB[7]) << 16);
      As[(wave * 16 + li) * 16 + (ri ^ li)] = oA;
      As[(wave * 16 + li) * 16 + ((ri + 1) ^ li)] = oB;
    }
  }
  // no barrier: each wave reads only its own slice (lgkmcnt orders ds ops within a wave)

  float4v acc[8];
#pragma unroll
  for (int c2 = 0; c2 < 8; c2++)
#pragma unroll
    for (int i = 0; i < 4; i++) acc[c2][i] = 0.f;

  // ---- Phase 2a: agg @ Wrel (wbF kc 0..3) ----
#pragma unroll
  for (int kc = 0; kc < 4; kc++) {
    int c = kc * 4 + sub;
    short8v afr = *(const short8v*)&As[(wave * 16 + c) * 16 + (li ^ c)];
#pragma unroll
    for (int c2 = 0; c2 < 8; c2++) {
      short8v bfr = *(const short8v*)(wbF + (size_t)((kc * 8 + c2) * 64 + lane) * 8);
      acc[c2] = __builtin_amdgcn_mfma_f32_16x16x32_bf16(afr, bfr, acc[c2], 0, 0, 0);
    }
  }

  // ---- restage own 16 h rows into same LDS slice (no barrier needed: own slice) ----
#pragma unroll
  for (int j = 0; j < 4; j++) {
    int idx = j * 64 + lane;
    int r = idx >> 4, c = idx & 15;
    int rsrc = wrow0 + r; if (rsrc > N_NODES - 1) rsrc = N_NODES - 1;
    uint4 v = *(const uint4*)(hIn + (size_t)rsrc * DIM + c * 8);
    As[(wave * 16 + c) * 16 + (r ^ c)] = v;
  }

  // ---- Phase 2b: h @ Wroot (wbF kc 4..7) ----
#pragma unroll
  for (int kc = 0; kc < 4; kc++) {
    int c = kc * 4 + sub;
    short8v afr = *(const short8v*)&As[(wave * 16 + c) * 16 + (li ^ c)];
#pragma unroll
    for (int c2 = 0; c2 < 8; c2++) {
      short8v bfr = *(const short8v*)(wbF + (size_t)(((4 + kc) * 8 + c2) * 64 + lane) * 8);
      acc[c2] = __builtin_amdgcn_mfma_f32_16x16x32_bf16(afr, bfr, acc[c2], 0, 0, 0);
    }
  }

  // ---- epilogue: D layout col = lane&15, row = (lane>>4)*4 + i ----
  int rbase = wrow0 + sub * 4;
#pragma unroll
  for (int c2 = 0; c2 < 8; c2++) {
    int colidx = c2 * 16 + li;
    float bv = bias[colidx];
#pragma unroll
    for (int i = 0; i < 4; i++) {
      int row = rbase + i;
      if (row < N_NODES) {
        float v = acc[c2][i] + bv;
        v = v > 0.f ? v : 0.f;
        hOut[row * DIM + colidx] = f2bf(v);
      }
    }
  }
}

// ---------------- pooling: one wave per graph, flat uint4 streaming, no atomics ----------------
__global__ __launch_bounds__(256) void k_pool(const unsigned short* __restrict__ h,
                                              const int* __restrict__ gptr,
                                              float* __restrict__ pooledMean) {
  int g = blockIdx.x * 4 + (threadIdx.x >> 6);
  if (g >= N_GRAPHS) return;
  int lane = threadIdx.x & 63;
  int li = lane & 15;
  int s0 = gptr[g], s1 = gptr[g + 1];
  float p[8];
#pragma unroll
  for (int j = 0; j < 8; j++) p[j] = 0.f;
  int f1 = s1 * 16;
  for (int f = s0 * 16 + lane; f < f1; f += 64) {
    uint4 v = ((const uint4*)h)[f];
    accum8(p, v);
  }
#pragma unroll
  for (int j = 0; j < 8; j++) {
    p[j] += __shfl_xor(p[j], 16, 64);
    p[j] += __shfl_xor(p[j], 32, 64);
  }
  float inv = (s1 > s0) ? 1.f / (float)(s1 - s0) : 0.f;
  if (lane < 16) {
    float4 o0 = make_float4(p[0] * inv, p[1] * inv, p[2] * inv, p[3] * inv);
    float4 o1 = make_float4(p[4] * inv, p[5] * inv, p[6] * inv, p[7] * inv);
    *(float4*)(pooledMean + g * DIM + li * 8) = o0;
    *(float4*)(pooledMean + g * DIM + li * 8 + 4) = o1;
  }
}

// ---------------- fused FC head ----------------
__global__ __launch_bounds__(256) void k_fc(const float* __restrict__ pooledMean,
                                            const float* __restrict__ fc_w, const float* __restrict__ fc_b,
                                            const float* __restrict__ reg_w, const float* __restrict__ reg_b,
                                            float* __restrict__ out) {
  __shared__ float sp[128];
  __shared__ float shfc[256];
  __shared__ float red[64];
  int g = blockIdx.x, t = threadIdx.x;
  if (t < 128) sp[t] = pooledMean[g * DIM + t];
  __syncthreads();
  float a = fc_b[t];
  for (int k = 0; k < 128; k++) a += sp[k] * fc_w[k * 256 + t];
  shfc[t] = a;
  __syncthreads();
  if (t < 64) {
    int o = t & 7, seg = t >> 3;
    float r = 0.f;
    for (int j = seg * 32; j < seg * 32 + 32; j++) r += shfc[j] * reg_w[j * 8 + o];
    red[t] = r;
  }
  __syncthreads();
  if (t < 8) {
    float r = reg_b[t];
    for (int s = 0; s < 8; s++) r += red[s * 8 + t];
    out[g * 8 + t] = r;
  }
}

extern "C" void kernel_launch(void* const* d_in, const int* in_sizes, int n_in,
                              void* d_out, int out_size, void* d_ws, size_t ws_size,
                              hipStream_t stream) {
  (void)in_sizes; (void)n_in; (void)out_size; (void)ws_size;
  const float* x = (const float*)d_in[0];
  const int* ei = (const int*)d_in[1];
  const int* src = ei;
  const int* dst = ei + N_EDGES;
  const int* batch = (const int*)d_in[2];
  const float* Wrel[4]  = {(const float*)d_in[3], (const float*)d_in[6], (const float*)d_in[9],  (const float*)d_in[12]};
  const float* Wroot[4] = {(const float*)d_in[4], (const float*)d_in[7], (const float*)d_in[10], (const float*)d_in[13]};
  const float* bias[4]  = {(const float*)d_in[5], (const float*)d_in[8], (const float*)d_in[11], (const float*)d_in[14]};
  const float* fc_w  = (const float*)d_in[15];
  const float* fc_b  = (const float*)d_in[16];
  const float* reg_w = (const float*)d_in[17];
  const float* reg_b = (const float*)d_in[18];
  float* out = (float*)d_out;

  char* ws = (char*)d_ws;
  size_t off = 0;
  auto alloc = [&](size_t b) -> char* {
    char* p = ws + off;
    off = (off + b + 255) & ~(size_t)255;
    return p;
  };
  int* rowptr = (int*)alloc((N_NODES + 1) * 4);
  int* cntmat = (int*)alloc((size_t)NMAT * 4);
  int* tmpB   = (int*)alloc((size_t)NMAT * 4);
  int* bsumB  = (int*)alloc(128 * 4);
  int* base   = (int*)alloc((size_t)NMAT * 4);
  int2* epk   = (int2*)alloc((size_t)N_EDGES * 8);
  int* colws  = (int*)alloc((size_t)N_EDGES * 4);
  int* gptr   = (int*)alloc((N_GRAPHS + 1) * 4);
  unsigned short* wbF = (unsigned short*)alloc((size_t)4 * 32768 * 2);
  unsigned short* h_a = (unsigned short*)alloc((size_t)N_NODES * DIM * 2);
  unsigned short* h_b = (unsigned short*)alloc((size_t)N_NODES * DIM * 2);
  float* pooled = (float*)alloc((size_t)N_GRAPHS * DIM * 4);

  // bucket CSR build: zero global atomics
  k_bcount<<<NCH, 256, 0, stream>>>(dst, cntmat);
  k_scan1g<<<NMAT / 1024, 256, 0, stream>>>(cntmat, NMAT, tmpB, bsumB);   // 49 blocks
  k_scan2g<<<1, 128, 0, stream>>>(bsumB, NMAT / 1024);
  k_exc<<<(NMAT + 255) / 256, 256, 0, stream>>>(tmpB, bsumB, cntmat, NMAT, base);
  k_bscatter<<<NCH, 256, 0, stream>>>(src, dst, base, epk);
  k_bfinish<<<NBUK, 256, 0, stream>>>(epk, base, rowptr, colws);

  k_gptr<<<(N_NODES + 255) / 256, 256, 0, stream>>>(batch, gptr);
  k_cvtx<<<(N_NODES * DIM / 4 + 255) / 256, 256, 0, stream>>>(x, h_a);
  k_cvtw<<<(4 * 32768 + 255) / 256, 256, 0, stream>>>(
      Wrel[0], Wroot[0], Wrel[1], Wroot[1], Wrel[2], Wroot[2], Wrel[3], Wroot[3], wbF);

  unsigned short* h_in = h_a;
  unsigned short* h_out = h_b;
  const int FB = (N_NODES + 63) / 64;  // 1563 blocks, 6.1/CU < 8 cap -> fully resident
  for (int l = 0; l < 4; l++) {
    k_fused<<<FB, 256, 0, stream>>>(rowptr, colws, h_in, wbF + (size_t)l * 32768, bias[l], h_out);
    unsigned short* t2 = h_in; h_in = h_out; h_out = t2;
  }
  // after 4 swaps, final features are in h_in (== h_a)

  k_pool<<<(N_GRAPHS + 3) / 4, 256, 0, stream>>>(h_in, gptr, pooled);
  k_fc<<<N_GRAPHS, 256, 0, stream>>>(pooled, fc_w, fc_b, reg_w, reg_b, out);
}